// Round 10
// baseline (144.063 us; speedup 1.0000x reference)
//
#include <hip/hip_runtime.h>
#include <stdint.h>
#include <math.h>

// Problem constants
#define BATCH 4096
#define NT    8192          // 2*BATCH
#define FD    256           // feature dim
#define TILE  128           // block tile (square)
#define NUMK  5
#define NTRI  2080          // 64*65/2 triangle tiles; %8==0
#define PBLK  1024          // prep blocks (8 rows each)

typedef __attribute__((ext_vector_type(8))) short bf16x8;  // 8 bf16 = 4 VGPRs
typedef __attribute__((ext_vector_type(4))) float f32x4;

// ---- workspace layout (bytes) ----
// fb 4 MiB | sq 32 KiB | pcol 1 MiB | wsum 4 KiB | gamma 4 B
static const size_t WS_FB    = 0;
static const size_t WS_SQ    = (size_t)NT * FD * 2;              // 4194304
static const size_t WS_PCOL  = WS_SQ + (size_t)NT * 4;           // +32768
static const size_t WS_WSUM  = WS_PCOL + (size_t)PBLK * 256 * 4; // +1 MiB
static const size_t WS_GAMMA = WS_WSUM + (size_t)PBLK * 4;       // +4 KiB

__device__ __forceinline__ unsigned short f2bf_rne(float x) {
    unsigned u = __float_as_uint(x);
    unsigned r = (u + 0x7fffu + ((u >> 16) & 1u)) >> 16;
    return (unsigned short)r;
}

// ---------------- kernel 1: convert + row norms + per-block partials ----------
__global__ void mmd_prep(const float* __restrict__ s_feat,
                         const float* __restrict__ t_feat,
                         unsigned short* __restrict__ fb,
                         float* __restrict__ sq,
                         float* __restrict__ pcol,
                         float* __restrict__ wsum) {
    __shared__ float cp[4][FD];
    __shared__ float rw[4];
    const int w    = threadIdx.x >> 6;
    const int lane = threadIdx.x & 63;
    float c0 = 0.f, c1 = 0.f, c2 = 0.f, c3 = 0.f;
    float wtot = 0.f;
#pragma unroll
    for (int t = 0; t < 2; ++t) {
        int row = blockIdx.x * 8 + w * 2 + t;
        const float* src = (row < BATCH) ? (s_feat + (size_t)row * FD)
                                         : (t_feat + (size_t)(row - BATCH) * FD);
        float4 v = ((const float4*)src)[lane];
        unsigned int u01 = (unsigned)f2bf_rne(v.x) | ((unsigned)f2bf_rne(v.y) << 16);
        unsigned int u23 = (unsigned)f2bf_rne(v.z) | ((unsigned)f2bf_rne(v.w) << 16);
        ((uint2*)(fb + (size_t)row * FD))[lane] = make_uint2(u01, u23);
        float ss = v.x * v.x + v.y * v.y + v.z * v.z + v.w * v.w;
        for (int off = 32; off; off >>= 1) ss += __shfl_down(ss, off);
        if (lane == 0) { sq[row] = ss; wtot += ss; }
        c0 += v.x; c1 += v.y; c2 += v.z; c3 += v.w;
    }
    cp[w][4 * lane + 0] = c0;
    cp[w][4 * lane + 1] = c1;
    cp[w][4 * lane + 2] = c2;
    cp[w][4 * lane + 3] = c3;
    if (lane == 0) rw[w] = wtot;
    __syncthreads();
    int t = threadIdx.x;
    pcol[(size_t)blockIdx.x * 256 + t] = cp[0][t] + cp[1][t] + cp[2][t] + cp[3][t];
    if (t == 0) wsum[blockIdx.x] = rw[0] + rw[1] + rw[2] + rw[3];
}

// ---------------- kernel 2: reduce partials -> gamma0; zero out ----------------
__global__ void mmd_gamma(const float* __restrict__ pcol,
                          const float* __restrict__ wsum,
                          float* __restrict__ gamma,
                          float* __restrict__ out) {
    __shared__ float gcol[4][256];
    __shared__ float redc[4], redw[16];
    const int tid  = threadIdx.x;        // 1024 threads
    const int c    = tid & 255, s = tid >> 8;
    const int lane = tid & 63;
    float a0 = 0.f, a1 = 0.f, a2 = 0.f, a3 = 0.f;
#pragma unroll 4
    for (int k = 0; k < 256; k += 4) {
        a0 += pcol[(size_t)(s * 256 + k + 0) * 256 + c];
        a1 += pcol[(size_t)(s * 256 + k + 1) * 256 + c];
        a2 += pcol[(size_t)(s * 256 + k + 2) * 256 + c];
        a3 += pcol[(size_t)(s * 256 + k + 3) * 256 + c];
    }
    gcol[s][c] = (a0 + a1) + (a2 + a3);
    float wv = wsum[tid];
    for (int off = 32; off; off >>= 1) wv += __shfl_down(wv, off);
    if (lane == 0) redw[tid >> 6] = wv;
    __syncthreads();
    if (tid < 256) {
        float colv = gcol[0][c] + gcol[1][c] + gcol[2][c] + gcol[3][c];
        float cv2 = colv * colv;
        for (int off = 32; off; off >>= 1) cv2 += __shfl_down(cv2, off);
        if (lane == 0) redc[tid >> 6] = cv2;
    }
    __syncthreads();
    if (tid == 0) {
        float s2 = (redc[0] + redc[1]) + (redc[2] + redc[3]);
        float ssq = 0.f;
#pragma unroll
        for (int i = 0; i < 16; ++i) ssq += redw[i];
        float sumd = 2.0f * (float)NT * ssq - 2.0f * s2;
        float n2n  = (float)((long long)NT * NT - NT);   // n^2 - n
        gamma[0]   = 0.25f * (n2n / sumd);   // bw / 2^(NUM_KERNELS//2)
        out[0]     = 0.f;
    }
}

// ---------------- kernel 3: fused GEMM + gaussian-kernel + reduce ----------------
// LDS-FREE K-loop: MFMA fragments load straight from global (fb is L2-resident;
// fragment = 8 contiguous bf16, verified bit-exact in round 1) with an explicit
// 3-deep register rotation: af/bf[3][4]. Chunk st+3 is issued right after the
// MFMAs that free slot st%3, so every fragment has ~3 K-steps (>L2 latency) in
// flight. No DMA, no ds_read, no lgkm waits, no barriers in the loop — the
// compiler inserts counted vmcnt before each slot's first MFMA use.
__global__ __launch_bounds__(256, 2) void mmd_main(
    const unsigned short* __restrict__ fb,
    const float* __restrict__ sq,
    const float* __restrict__ gamma,
    float* __restrict__ out) {
    // XCD-chunked swizzle (NTRI % 8 == 0 -> bijective)
    const int bid = blockIdx.x;
    const int swz = (bid & 7) * (NTRI / 8) + (bid >> 3);
    // decode linear triangle index -> (bi <= bj)
    int r = (int)((sqrtf(8.0f * (float)swz + 1.0f) - 1.0f) * 0.5f);
    while ((r + 1) * (r + 2) / 2 <= swz) ++r;
    while (r * (r + 1) / 2 > swz) --r;
    const int bi = swz - r * (r + 1) / 2;   // 0..r
    const int bj = r;

    __shared__ float sqa[TILE], sqb[TILE];
    __shared__ float red[4];

    const int tid  = threadIdx.x;
    const int w    = tid >> 6, lane = tid & 63;
    const int wm   = w >> 1, wn = w & 1;         // 2x2 waves over 128x128
    const int quad = lane >> 4, m16 = lane & 15;

    // per-lane fragment base pointers (fragment = 8 contiguous bf16 of a row)
    const unsigned short* pa =
        fb + ((size_t)bi * TILE + wm * 64 + m16) * FD + quad * 8;
    const unsigned short* pb =
        fb + ((size_t)bj * TILE + wn * 64 + m16) * FD + quad * 8;

    // 3-deep fragment rotation: issue chunks 0..2 immediately (deep in flight)
    bf16x8 af[3][4], bf[3][4];
#pragma unroll
    for (int s = 0; s < 3; ++s) {
#pragma unroll
        for (int tm = 0; tm < 4; ++tm)
            af[s][tm] = *(const bf16x8*)(pa + tm * 16 * FD + s * 32);
#pragma unroll
        for (int tn = 0; tn < 4; ++tn)
            bf[s][tn] = *(const bf16x8*)(pb + tn * 16 * FD + s * 32);
    }
    __builtin_amdgcn_sched_barrier(0);   // prologue loads stay first

    // epilogue scalars (L2-hot; issued behind the fragment loads)
    float sqv = 0.f;
    if (tid < TILE) sqv = sq[(size_t)bi * TILE + tid];
    else            sqv = sq[(size_t)bj * TILE + (tid - TILE)];
    const float g0 = gamma[0];
    if (tid < TILE) sqa[tid] = sqv;
    else            sqb[tid - TILE] = sqv;

    const f32x4 fzero = {0.f, 0.f, 0.f, 0.f};
    f32x4 acc[4][4];
#pragma unroll
    for (int a = 0; a < 4; ++a)
#pragma unroll
        for (int b = 0; b < 4; ++b) acc[a][b] = fzero;

    // -------- barrier-free K-loop (8 chunks of K=32) --------
#pragma unroll
    for (int st = 0; st < 8; ++st) {
        const int cur = st % 3;   // compile-time after full unroll

        __builtin_amdgcn_s_setprio(1);
#pragma unroll
        for (int tm = 0; tm < 4; ++tm)
#pragma unroll
            for (int tn = 0; tn < 4; ++tn)
                acc[tm][tn] = __builtin_amdgcn_mfma_f32_16x16x32_bf16(
                    af[cur][tm], bf[cur][tn], acc[tm][tn], 0, 0, 0);
        __builtin_amdgcn_s_setprio(0);
        __builtin_amdgcn_sched_barrier(0);   // loads below stay below the MFMAs

        if (st <= 4) {   // refill freed slot with chunk st+3
#pragma unroll
            for (int tm = 0; tm < 4; ++tm)
                af[cur][tm] = *(const bf16x8*)(pa + tm * 16 * FD + (st + 3) * 32);
#pragma unroll
            for (int tn = 0; tn < 4; ++tn)
                bf[cur][tn] = *(const bf16x8*)(pb + tn * 16 * FD + (st + 3) * 32);
        }
        __builtin_amdgcn_sched_barrier(0);   // ... and above the next step
    }

    __syncthreads();   // only block-wide sync: sqa/sqb visible for epilogue

    // ---- epilogue: d = sq_i + sq_j - 2 dot, clamp, e + e^2 + e^4 + e^8 + e^16 ----
    float ls[4] = {0.f, 0.f, 0.f, 0.f};
#pragma unroll
    for (int tm = 0; tm < 4; ++tm) {
        const int i0 = wm * 64 + tm * 16 + quad * 4;
        float sqi[4] = {sqa[i0 + 0], sqa[i0 + 1], sqa[i0 + 2], sqa[i0 + 3]};
#pragma unroll
        for (int tn = 0; tn < 4; ++tn) {
            const int j = wn * 64 + tn * 16 + m16;
            const float sqj = sqb[j];
#pragma unroll
            for (int rr = 0; rr < 4; ++rr) {
                float d = fmaf(-2.f, acc[tm][tn][rr], sqi[rr] + sqj);
                d = fmaxf(d, 0.f);
                float e1 = __expf(-d * g0);
                float e2 = e1 * e1, e4 = e2 * e2, e8 = e4 * e4, e16 = e8 * e8;
                ls[rr] += e1 + e2 + e4 + e8 + e16;
            }
        }
    }
    float lsum = (ls[0] + ls[1]) + (ls[2] + ls[3]);
    for (int off = 32; off; off >>= 1) lsum += __shfl_down(lsum, off);
    if (lane == 0) red[w] = lsum;
    __syncthreads();
    if (tid == 0) {
        float wgt;
        if (bi == bj) wgt = 1.f;                                  // diagonal tile, once
        else wgt = ((bi < 32) == (bj < 32)) ? 2.f : -2.f;         // mirrored tile folded in
        float scale = wgt * (1.f / NUMK) * (1.f / 16777216.f);    // /(NUMK*4096^2)
        atomicAdd(out, (red[0] + red[1] + red[2] + red[3]) * scale);
    }
}

extern "C" void kernel_launch(void* const* d_in, const int* in_sizes, int n_in,
                              void* d_out, int out_size, void* d_ws, size_t ws_size,
                              hipStream_t stream) {
    const float* s_feat = (const float*)d_in[0];
    const float* t_feat = (const float*)d_in[1];
    char* ws = (char*)d_ws;
    unsigned short* fb = (unsigned short*)(ws + WS_FB);
    float* sq    = (float*)(ws + WS_SQ);
    float* pcol  = (float*)(ws + WS_PCOL);
    float* wsum  = (float*)(ws + WS_WSUM);
    float* gamma = (float*)(ws + WS_GAMMA);
    float* out   = (float*)d_out;

    mmd_prep<<<PBLK, 256, 0, stream>>>(s_feat, t_feat, fb, sq, pcol, wsum);
    mmd_gamma<<<1, 1024, 0, stream>>>(pcol, wsum, gamma, out);
    mmd_main<<<NTRI, 256, 0, stream>>>(fb, sq, gamma, out);
}

// Round 11
// 141.878 us; speedup vs baseline: 1.0154x; 1.0154x over previous
//
#include <hip/hip_runtime.h>
#include <stdint.h>
#include <math.h>

// Problem constants
#define BATCH 4096
#define NT    8192          // 2*BATCH
#define FD    256           // feature dim
#define TILE  128           // tile edge (rows per panel / cols per tile)
#define BK    32            // K chunk (8 chunks of K=32)
#define NUMK  5
#define NSTRIP 544          // sum_{bi} ceil((64-bi)/4); %8==0
#define PBLK  1024          // prep blocks (8 rows each)

typedef __attribute__((ext_vector_type(8))) short bf16x8;  // 8 bf16 = 4 VGPRs
typedef __attribute__((ext_vector_type(4))) float f32x4;

// ---- workspace layout (bytes) ----
// fb 4 MiB | sq 32 KiB | pcol 1 MiB | wsum 4 KiB | gamma 4 B
static const size_t WS_FB    = 0;
static const size_t WS_SQ    = (size_t)NT * FD * 2;              // 4194304
static const size_t WS_PCOL  = WS_SQ + (size_t)NT * 4;           // +32768
static const size_t WS_WSUM  = WS_PCOL + (size_t)PBLK * 256 * 4; // +1 MiB
static const size_t WS_GAMMA = WS_WSUM + (size_t)PBLK * 4;       // +4 KiB

__device__ __forceinline__ unsigned short f2bf_rne(float x) {
    unsigned u = __float_as_uint(x);
    unsigned r = (u + 0x7fffu + ((u >> 16) & 1u)) >> 16;
    return (unsigned short)r;
}

__device__ __forceinline__ void async_copy16(void* lds, const void* g) {
    __builtin_amdgcn_global_load_lds(
        (__attribute__((address_space(1))) void*)(void*)(const_cast<void*>(g)),
        (__attribute__((address_space(3))) void*)lds, 16, 0, 0);
}

// ---------------- kernel 1: convert + row norms + per-block partials ----------
__global__ void mmd_prep(const float* __restrict__ s_feat,
                         const float* __restrict__ t_feat,
                         unsigned short* __restrict__ fb,
                         float* __restrict__ sq,
                         float* __restrict__ pcol,
                         float* __restrict__ wsum) {
    __shared__ float cp[4][FD];
    __shared__ float rw[4];
    const int w    = threadIdx.x >> 6;
    const int lane = threadIdx.x & 63;
    float c0 = 0.f, c1 = 0.f, c2 = 0.f, c3 = 0.f;
    float wtot = 0.f;
#pragma unroll
    for (int t = 0; t < 2; ++t) {
        int row = blockIdx.x * 8 + w * 2 + t;
        const float* src = (row < BATCH) ? (s_feat + (size_t)row * FD)
                                         : (t_feat + (size_t)(row - BATCH) * FD);
        float4 v = ((const float4*)src)[lane];
        unsigned int u01 = (unsigned)f2bf_rne(v.x) | ((unsigned)f2bf_rne(v.y) << 16);
        unsigned int u23 = (unsigned)f2bf_rne(v.z) | ((unsigned)f2bf_rne(v.w) << 16);
        ((uint2*)(fb + (size_t)row * FD))[lane] = make_uint2(u01, u23);
        float ss = v.x * v.x + v.y * v.y + v.z * v.z + v.w * v.w;
        for (int off = 32; off; off >>= 1) ss += __shfl_down(ss, off);
        if (lane == 0) { sq[row] = ss; wtot += ss; }
        c0 += v.x; c1 += v.y; c2 += v.z; c3 += v.w;
    }
    cp[w][4 * lane + 0] = c0;
    cp[w][4 * lane + 1] = c1;
    cp[w][4 * lane + 2] = c2;
    cp[w][4 * lane + 3] = c3;
    if (lane == 0) rw[w] = wtot;
    __syncthreads();
    int t = threadIdx.x;
    pcol[(size_t)blockIdx.x * 256 + t] = cp[0][t] + cp[1][t] + cp[2][t] + cp[3][t];
    if (t == 0) wsum[blockIdx.x] = rw[0] + rw[1] + rw[2] + rw[3];
}

// ---------------- kernel 2: reduce partials -> gamma0; zero out ----------------
__global__ void mmd_gamma(const float* __restrict__ pcol,
                          const float* __restrict__ wsum,
                          float* __restrict__ gamma,
                          float* __restrict__ out) {
    __shared__ float gcol[4][256];
    __shared__ float redc[4], redw[16];
    const int tid  = threadIdx.x;        // 1024 threads
    const int c    = tid & 255, s = tid >> 8;
    const int lane = tid & 63;
    float a0 = 0.f, a1 = 0.f, a2 = 0.f, a3 = 0.f;
#pragma unroll 4
    for (int k = 0; k < 256; k += 4) {
        a0 += pcol[(size_t)(s * 256 + k + 0) * 256 + c];
        a1 += pcol[(size_t)(s * 256 + k + 1) * 256 + c];
        a2 += pcol[(size_t)(s * 256 + k + 2) * 256 + c];
        a3 += pcol[(size_t)(s * 256 + k + 3) * 256 + c];
    }
    gcol[s][c] = (a0 + a1) + (a2 + a3);
    float wv = wsum[tid];
    for (int off = 32; off; off >>= 1) wv += __shfl_down(wv, off);
    if (lane == 0) redw[tid >> 6] = wv;
    __syncthreads();
    if (tid < 256) {
        float colv = gcol[0][c] + gcol[1][c] + gcol[2][c] + gcol[3][c];
        float cv2 = colv * colv;
        for (int off = 32; off; off >>= 1) cv2 += __shfl_down(cv2, off);
        if (lane == 0) redc[tid >> 6] = cv2;
    }
    __syncthreads();
    if (tid == 0) {
        float s2 = (redc[0] + redc[1]) + (redc[2] + redc[3]);
        float ssq = 0.f;
#pragma unroll
        for (int i = 0; i < 16; ++i) ssq += redw[i];
        float sumd = 2.0f * (float)NT * ssq - 2.0f * s2;
        float n2n  = (float)((long long)NT * NT - NT);   // n^2 - n
        gamma[0]   = 0.25f * (n2n / sumd);   // bw / 2^(NUM_KERNELS//2)
        out[0]     = 0.f;
    }
}

// ---------------- kernel 3: strip-persistent fused GEMM+kernel+reduce ----------
// Block = 512 thr (8 waves, 2Mx4N over 128x128). Each block processes a strip
// of up to 4 consecutive j-tiles of one 128-row panel: A is loaded ONCE into
// registers (32 bf16x8/lane); B streams through a 3x8KB LDS ring with the
// r4-proven counted-vmcnt schedule, CONTINUOUSLY across tile boundaries, so
// the pipeline fills once per strip (not once per tile) and each tile's
// epilogue overlaps the next tile's B prefetch. Epilogue reads sq straight
// from global (L2-hot) premultiplied by gamma*log2e; exp via native exp2.
__global__ __launch_bounds__(512, 2) void mmd_main(
    const unsigned short* __restrict__ fb,
    const float* __restrict__ sq,
    const float* __restrict__ gamma,
    float* __restrict__ out) {
    // XCD-chunked swizzle (NSTRIP % 8 == 0 -> bijective)
    const int bid = blockIdx.x;
    const int swz = (bid & 7) * (NSTRIP / 8) + (bid >> 3);
    // decode strip -> (bi, j0, len): row bi has ceil((64-bi)/4) strips
    int bi = 0, rem = swz;
    for (;;) {
        int ns = (64 - bi + 3) >> 2;
        if (rem < ns) break;
        rem -= ns; ++bi;
    }
    const int j0  = bi + rem * 4;
    const int len = (64 - j0 < 4) ? (64 - j0) : 4;
    const int M   = len * 8;                 // total K-chunks in strip

    __shared__ __align__(16) unsigned short b_lds[3][TILE * BK];  // 3 x 8 KiB
    __shared__ float red[8];

    const int tid  = threadIdx.x;
    const int w    = tid >> 6, lane = tid & 63;
    const int wm   = w >> 2, wn = w & 3;     // 2x4 waves: 64-row x 32-col each
    const int quad = lane >> 4, m16 = lane & 15;

    // ---- A-panel into registers: 32 frags (8 chunks x 4 row-frags) ----
    const size_t rowA0 = (size_t)bi * TILE + wm * 64;
    const unsigned short* pa = fb + (rowA0 + m16) * FD + quad * 8;
    bf16x8 ar[32];
#pragma unroll
    for (int c = 0; c < 8; ++c)
#pragma unroll
        for (int tm = 0; tm < 4; ++tm)
            ar[c * 4 + tm] = *(const bf16x8*)(pa + tm * 16 * FD + c * 32);

    // row norms for this panel (float4 x4), gamma (scalar)
    const float g0 = gamma[0];
    float sqi4[16];
    {
        const size_t ib = (size_t)bi * TILE + wm * 64 + quad * 4;
#pragma unroll
        for (int tm = 0; tm < 4; ++tm) {
            float4 v = *(const float4*)&sq[ib + tm * 16];
            sqi4[tm * 4 + 0] = v.x; sqi4[tm * 4 + 1] = v.y;
            sqi4[tm * 4 + 2] = v.z; sqi4[tm * 4 + 3] = v.w;
        }
    }

    // ---- B staging: chunk m covers tile j0+(m>>3), k = (m&7)*32 ----
#define STAGE_B(slot, m2) do {                                                 \
        int jt_  = j0 + ((m2) >> 3);                                           \
        int c2_  = (m2) & 7;                                                   \
        int row_ = w * 16 + (lane >> 2);      /* 0..127 */                     \
        int p_   = lane & 3;                                                   \
        int gc_  = p_ ^ ((row_ >> 1) & 3);                                     \
        async_copy16(&b_lds[slot][(w * 16) * BK],                              \
                     fb + ((size_t)jt_ * TILE + row_) * FD + c2_ * 32 + gc_ * 8); \
    } while (0)

    STAGE_B(0, 0);
    STAGE_B(1, 1);

    const float Gp   = g0 * 1.44269504f;     // gamma * log2(e)
    const float twoG = 2.0f * Gp;
    float sgiG[16];
#pragma unroll
    for (int i = 0; i < 16; ++i) sgiG[i] = sqi4[i] * Gp;

    float wacc = 0.f;
    const f32x4 fzero = {0.f, 0.f, 0.f, 0.f};

    // ---- one tile: 8 chunks (continuous schedule) + epilogue ----
#define TILE_BODY(T) do {                                                      \
        const int bj_ = j0 + (T);                                              \
        const float sgjG0_ = sq[(size_t)bj_ * TILE + wn * 32 + m16] * Gp;      \
        const float sgjG1_ = sq[(size_t)bj_ * TILE + wn * 32 + 16 + m16] * Gp; \
        f32x4 acc[4][2];                                                       \
        _Pragma("unroll")                                                      \
        for (int a = 0; a < 4; ++a) { acc[a][0] = fzero; acc[a][1] = fzero; }  \
        _Pragma("unroll")                                                      \
        for (int c = 0; c < 8; ++c) {                                          \
            const int m = (T) * 8 + c;                                         \
            /* certify chunk m (staged 2 chunks ago); keep m+1 in flight */    \
            if (m == M - 1) asm volatile("s_waitcnt vmcnt(0)" ::: "memory");   \
            else            asm volatile("s_waitcnt vmcnt(1)" ::: "memory");   \
            __builtin_amdgcn_s_barrier();                                      \
            __builtin_amdgcn_sched_barrier(0);                                 \
            if (m + 2 < M) STAGE_B((m + 2) % 3, m + 2);                        \
            const unsigned short* bt_ = &b_lds[m % 3][0];                      \
            bf16x8 bf0_, bf1_;                                                 \
            { int row = wn * 32 + m16;      int p = quad ^ ((row >> 1) & 3);   \
              bf0_ = *(const bf16x8*)&bt_[row * BK + p * 8]; }                 \
            { int row = wn * 32 + 16 + m16; int p = quad ^ ((row >> 1) & 3);   \
              bf1_ = *(const bf16x8*)&bt_[row * BK + p * 8]; }                 \
            __builtin_amdgcn_sched_barrier(0);                                 \
            __builtin_amdgcn_s_setprio(1);                                     \
            _Pragma("unroll")                                                  \
            for (int tm = 0; tm < 4; ++tm) {                                   \
                acc[tm][0] = __builtin_amdgcn_mfma_f32_16x16x32_bf16(          \
                    ar[c * 4 + tm], bf0_, acc[tm][0], 0, 0, 0);                \
                acc[tm][1] = __builtin_amdgcn_mfma_f32_16x16x32_bf16(          \
                    ar[c * 4 + tm], bf1_, acc[tm][1], 0, 0, 0);                \
            }                                                                  \
            __builtin_amdgcn_s_setprio(0);                                     \
        }                                                                      \
        float l0 = 0.f, l1 = 0.f, l2 = 0.f, l3 = 0.f;                          \
        _Pragma("unroll")                                                      \
        for (int tm = 0; tm < 4; ++tm) {                                       \
            _Pragma("unroll")                                                  \
            for (int tn = 0; tn < 2; ++tn) {                                   \
                const float sgj = tn ? sgjG1_ : sgjG0_;                        \
                _Pragma("unroll")                                              \
                for (int rr = 0; rr < 4; ++rr) {                               \
                    float ex = fminf(fmaf(acc[tm][tn][rr], twoG,               \
                                          -(sgiG[tm * 4 + rr] + sgj)), 0.f);   \
                    float e1 = exp2f(ex);                                      \
                    float e2 = e1 * e1, e4 = e2 * e2, e8 = e4 * e4,            \
                          e16 = e8 * e8;                                       \
                    float s5 = (e1 + e2) + (e4 + e8) + e16;                    \
                    if (rr == 0) l0 += s5; else if (rr == 1) l1 += s5;         \
                    else if (rr == 2) l2 += s5; else l3 += s5;                  \
                }                                                              \
            }                                                                  \
        }                                                                      \
        float tls = (l0 + l1) + (l2 + l3);                                     \
        float wgt = (bi == bj_) ? 1.f                                          \
                  : (((bi < 32) == (bj_ < 32)) ? 2.f : -2.f);                  \
        wacc = fmaf(wgt, tls, wacc);                                           \
    } while (0)

    TILE_BODY(0);
    if (len > 1) TILE_BODY(1);
    if (len > 2) TILE_BODY(2);
    if (len > 3) TILE_BODY(3);

    // ---- block reduce + single atomic ----
    for (int off = 32; off; off >>= 1) wacc += __shfl_down(wacc, off);
    if (lane == 0) red[w] = wacc;
    __syncthreads();
    if (tid == 0) {
        float tot = ((red[0] + red[1]) + (red[2] + red[3]))
                  + ((red[4] + red[5]) + (red[6] + red[7]));
        // weights already applied per tile; scale = 1/(NUMK*4096^2)
        atomicAdd(out, tot * ((1.f / NUMK) * (1.f / 16777216.f)));
    }
}

extern "C" void kernel_launch(void* const* d_in, const int* in_sizes, int n_in,
                              void* d_out, int out_size, void* d_ws, size_t ws_size,
                              hipStream_t stream) {
    const float* s_feat = (const float*)d_in[0];
    const float* t_feat = (const float*)d_in[1];
    char* ws = (char*)d_ws;
    unsigned short* fb = (unsigned short*)(ws + WS_FB);
    float* sq    = (float*)(ws + WS_SQ);
    float* pcol  = (float*)(ws + WS_PCOL);
    float* wsum  = (float*)(ws + WS_WSUM);
    float* gamma = (float*)(ws + WS_GAMMA);
    float* out   = (float*)d_out;

    mmd_prep<<<PBLK, 256, 0, stream>>>(s_feat, t_feat, fb, sq, pcol, wsum);
    mmd_gamma<<<1, 1024, 0, stream>>>(pcol, wsum, gamma, out);
    mmd_main<<<NSTRIP, 512, 0, stream>>>(fb, sq, gamma, out);
}